// Round 1
// baseline (29803.018 us; speedup 1.0000x reference)
//
#include <hip/hip_runtime.h>
#include <hip/hip_bf16.h>

// GRU: T=512, B=64, Cin=512, H=1024, 2 layers.
// Strategy: batch x-projections into big MFMA GEMMs; sequential part = 1024
// small per-step kernels (rz GEMM -> gates -> cand GEMM -> update).
// Precision: fp32 master h, hi/lo-split bf16 recurrent GEMM operands,
// fp32 storage for the cand x-projection.

#define Hh   1024
#define Bz   64
#define Tt   512
#define Mrows (Tt*Bz)   // 32768

typedef __attribute__((ext_vector_type(8))) short short8;
typedef __attribute__((ext_vector_type(4))) float f32x4;

__device__ __forceinline__ unsigned short f2bf(float f){
  unsigned u = __builtin_bit_cast(unsigned, f);
  u += 0x7fffu + ((u >> 16) & 1u);          // round-to-nearest-even
  return (unsigned short)(u >> 16);
}
__device__ __forceinline__ float bf2f(unsigned short s){
  unsigned u = ((unsigned)s) << 16;
  return __builtin_bit_cast(float, u);
}

__device__ __forceinline__ void gload16(const void* g, void* l){
  __builtin_amdgcn_global_load_lds(
      (const __attribute__((address_space(1))) unsigned int*)g,
      (__attribute__((address_space(3))) unsigned int*)l, 16, 0, 0);
}

// ---------------- prep kernels ----------------

__global__ __launch_bounds__(256) void k_cvt_bf16(const float* __restrict__ src,
                                                  unsigned short* __restrict__ dst, int n4){
  int i = blockIdx.x*blockDim.x + threadIdx.x;
  int stride = gridDim.x*blockDim.x;
  for (; i < n4; i += stride){
    float4 v = reinterpret_cast<const float4*>(src)[i];
    ushort4 o; o.x=f2bf(v.x); o.y=f2bf(v.y); o.z=f2bf(v.z); o.w=f2bf(v.w);
    reinterpret_cast<ushort4*>(dst)[i] = o;
  }
}

// fp32 (K,N) -> bf16 (N,K), 64x64 LDS tile
__global__ __launch_bounds__(256) void k_transpose_bf16(const float* __restrict__ src,
                                                        unsigned short* __restrict__ dst,
                                                        int K, int N){
  __shared__ float tile[64][65];
  int k0 = blockIdx.x * 64, n0 = blockIdx.y * 64;
  int t = threadIdx.x;
  int r = t >> 4, c4 = (t & 15) << 2;
  #pragma unroll
  for (int j = 0; j < 4; ++j){
    const float4 v = *reinterpret_cast<const float4*>(&src[(size_t)(k0 + r + j*16) * N + n0 + c4]);
    tile[r+j*16][c4+0]=v.x; tile[r+j*16][c4+1]=v.y;
    tile[r+j*16][c4+2]=v.z; tile[r+j*16][c4+3]=v.w;
  }
  __syncthreads();
  #pragma unroll
  for (int j = 0; j < 4; ++j){
    int nn = r + j*16;
    ushort4 o;
    o.x = f2bf(tile[c4+0][nn]); o.y = f2bf(tile[c4+1][nn]);
    o.z = f2bf(tile[c4+2][nn]); o.w = f2bf(tile[c4+3][nn]);
    *reinterpret_cast<ushort4*>(&dst[(size_t)(n0+nn)*K + k0 + c4]) = o;
  }
}

__global__ void k_bias_fold(const float* __restrict__ a, const float* __restrict__ b,
                            const float* __restrict__ c, const float* __restrict__ d,
                            float* __restrict__ out){
  int i = blockIdx.x*blockDim.x + threadIdx.x;
  if (i < 2048) out[i] = a[i] + b[i];
  else if (i < 3072) out[i] = c[i-2048] + d[i-2048];
}

// ---------------- big x-projection GEMM ----------------
// C(M,3072) = A(M,K)bf16 @ Bt(3072,K)^T + bias ; cols<2048 -> bf16 rz, else fp32 cand
__global__ __launch_bounds__(256) void k_xproj_gemm(
    const unsigned short* __restrict__ A, const unsigned short* __restrict__ Bt,
    const float* __restrict__ bias, unsigned short* __restrict__ outRZ,
    float* __restrict__ outC, int K)
{
  __shared__ __align__(16) unsigned short As[128*32];
  __shared__ __align__(16) unsigned short Bs[128*32];
  const int nb = blockIdx.x, mb = blockIdx.y;
  const int m0 = mb*128, n0 = nb*128;
  const int t = threadIdx.x, lane = t & 63, w = t >> 6;
  const int wr = w >> 1, wc = w & 1;
  const int lr = lane & 15, lq = lane >> 4;
  const int sr = t >> 2, scg = t & 3;
  f32x4 acc[4][4];
  const f32x4 zero4 = {0.f,0.f,0.f,0.f};
  #pragma unroll
  for (int mt=0;mt<4;++mt)
    #pragma unroll
    for (int nt=0;nt<4;++nt) acc[mt][nt] = zero4;

  const unsigned short* ga0 = &A [(size_t)(m0 + sr     )*K + scg*8];
  const unsigned short* ga1 = &A [(size_t)(m0 + sr + 64)*K + scg*8];
  const unsigned short* gb0 = &Bt[(size_t)(n0 + sr     )*K + scg*8];
  const unsigned short* gb1 = &Bt[(size_t)(n0 + sr + 64)*K + scg*8];
  char* lA = (char*)As + w*1024;
  char* lB = (char*)Bs + w*1024;
  const int kiters = K >> 5;
  for (int kt = 0; kt < kiters; ++kt){
    __syncthreads();
    gload16(ga0 + kt*32, lA);
    gload16(ga1 + kt*32, lA + 4096);
    gload16(gb0 + kt*32, lB);
    gload16(gb1 + kt*32, lB + 4096);
    asm volatile("s_waitcnt vmcnt(0)" ::: "memory");
    __syncthreads();
    short8 af[4], bfr[4];
    #pragma unroll
    for (int mt=0; mt<4; ++mt)
      af[mt] = *reinterpret_cast<const short8*>(&As[(wr*64 + mt*16 + lr)*32 + lq*8]);
    #pragma unroll
    for (int nt=0; nt<4; ++nt)
      bfr[nt] = *reinterpret_cast<const short8*>(&Bs[(wc*64 + nt*16 + lr)*32 + lq*8]);
    #pragma unroll
    for (int mt=0; mt<4; ++mt)
      #pragma unroll
      for (int nt=0; nt<4; ++nt)
        acc[mt][nt] = __builtin_amdgcn_mfma_f32_16x16x32_bf16(af[mt], bfr[nt], acc[mt][nt], 0,0,0);
  }
  const bool isRZ = (n0 < 2048);
  #pragma unroll
  for (int mt=0;mt<4;++mt){
    #pragma unroll
    for (int nt=0;nt<4;++nt){
      int gn = n0 + wc*64 + nt*16 + lr;
      float bv = bias[gn];
      #pragma unroll
      for (int i=0;i<4;++i){
        int gm = m0 + wr*64 + mt*16 + lq*4 + i;
        float v = acc[mt][nt][i] + bv;
        if (isRZ) outRZ[(size_t)gm*2048 + gn] = f2bf(v);
        else      outC [(size_t)gm*1024 + (gn - 2048)] = v;
      }
    }
  }
}

// ---------------- recurrent step kernels ----------------
// stepA: rz = xprz + [h_hi + h_lo] @ Wh_rz ; r-cols -> a = h*r (split hi/lo) ; z-cols -> zbuf
__global__ __launch_bounds__(256) void k_stepA(
    const unsigned short* __restrict__ hhi, const unsigned short* __restrict__ hlo,
    const unsigned short* __restrict__ Wt,   // (2048,1024) bf16, rows = n
    const unsigned short* __restrict__ xprz, // (64,2048) bf16 (biases folded in)
    const float* __restrict__ hfp,
    unsigned short* __restrict__ ahi, unsigned short* __restrict__ alo,
    float* __restrict__ zbuf)
{
  __shared__ __align__(16) unsigned short Ws[16*1032];  // +8 pad per row: no bank conflicts
  const int t = threadIdx.x, lane = t & 63, w = t >> 6;
  const int lr = lane & 15, lq = lane >> 4;
  const int n0 = blockIdx.x * 16;
  { // stage the 16-column W slice once (shared by all 4 waves)
    const int tr = t >> 4, tc = t & 15;
    const unsigned short* src = &Wt[(size_t)(n0 + tr)*1024 + tc*64];
    unsigned short* dst = &Ws[tr*1032 + tc*64];
    #pragma unroll
    for (int j = 0; j < 8; ++j)
      *reinterpret_cast<short8*>(dst + j*8) = *reinterpret_cast<const short8*>(src + j*8);
  }
  __syncthreads();
  const int arow = (w << 4) + lr;               // A row = lane&15 within band
  const unsigned short* hh = &hhi[arow << 10];
  const unsigned short* hl = &hlo[arow << 10];
  const unsigned short* wrow = &Ws[lr*1032];    // B col = lane&15
  f32x4 acc = {0.f,0.f,0.f,0.f};
  #pragma unroll 8
  for (int ks = 0; ks < 32; ++ks){
    const int kl = (ks << 5) + (lq << 3);
    short8 ah = *reinterpret_cast<const short8*>(hh + kl);
    short8 al = *reinterpret_cast<const short8*>(hl + kl);
    short8 bb = *reinterpret_cast<const short8*>(wrow + kl);
    acc = __builtin_amdgcn_mfma_f32_16x16x32_bf16(ah, bb, acc, 0,0,0);
    acc = __builtin_amdgcn_mfma_f32_16x16x32_bf16(al, bb, acc, 0,0,0);
  }
  #pragma unroll
  for (int i = 0; i < 4; ++i){
    const int b = (w << 4) + (lq << 2) + i;     // C row = (lane>>4)*4 + reg
    const int n = n0 + lr;                      // C col = lane&15
    float pre = acc[i] + bf2f(xprz[(b << 11) + n]);
    float s = 1.f / (1.f + __expf(-pre));
    if (n0 < 1024){
      float av = hfp[(b << 10) + n] * s;
      unsigned short hi = f2bf(av);
      ahi[(b << 10) + n] = hi;
      alo[(b << 10) + n] = f2bf(av - bf2f(hi));
    } else {
      zbuf[(b << 10) + n - 1024] = s;
    }
  }
}

// stepB: cand = tanh(xc + [a_hi+a_lo]@Wh_h); h' = z*h + (1-z)*cand
__global__ __launch_bounds__(256) void k_stepB(
    const unsigned short* __restrict__ ahi, const unsigned short* __restrict__ alo,
    const unsigned short* __restrict__ Wt,   // (1024,1024) bf16
    const float* __restrict__ xc,            // (64,1024) fp32
    const float* __restrict__ zbuf,
    float* __restrict__ hfp,
    unsigned short* __restrict__ out_hi, unsigned short* __restrict__ out_lo,
    float* __restrict__ fseq, float* __restrict__ hn)
{
  __shared__ __align__(16) unsigned short Ws[16*1032];
  const int t = threadIdx.x, lane = t & 63, w = t >> 6;
  const int lr = lane & 15, lq = lane >> 4;
  const int n0 = blockIdx.x * 16;
  {
    const int tr = t >> 4, tc = t & 15;
    const unsigned short* src = &Wt[(size_t)(n0 + tr)*1024 + tc*64];
    unsigned short* dst = &Ws[tr*1032 + tc*64];
    #pragma unroll
    for (int j = 0; j < 8; ++j)
      *reinterpret_cast<short8*>(dst + j*8) = *reinterpret_cast<const short8*>(src + j*8);
  }
  __syncthreads();
  const int arow = (w << 4) + lr;
  const unsigned short* ah_ = &ahi[arow << 10];
  const unsigned short* al_ = &alo[arow << 10];
  const unsigned short* wrow = &Ws[lr*1032];
  f32x4 acc = {0.f,0.f,0.f,0.f};
  #pragma unroll 8
  for (int ks = 0; ks < 32; ++ks){
    const int kl = (ks << 5) + (lq << 3);
    short8 ah = *reinterpret_cast<const short8*>(ah_ + kl);
    short8 al = *reinterpret_cast<const short8*>(al_ + kl);
    short8 bb = *reinterpret_cast<const short8*>(wrow + kl);
    acc = __builtin_amdgcn_mfma_f32_16x16x32_bf16(ah, bb, acc, 0,0,0);
    acc = __builtin_amdgcn_mfma_f32_16x16x32_bf16(al, bb, acc, 0,0,0);
  }
  #pragma unroll
  for (int i = 0; i < 4; ++i){
    const int b = (w << 4) + (lq << 2) + i;
    const int n = n0 + lr;
    float pre = acc[i] + xc[(b << 10) + n];
    float cand = tanhf(pre);
    float z = zbuf[(b << 10) + n];
    float h = hfp[(b << 10) + n];
    float hnew = z*h + (1.f - z)*cand;
    hfp[(b << 10) + n] = hnew;
    unsigned short hi = f2bf(hnew);
    out_hi[(b << 10) + n] = hi;
    out_lo[(b << 10) + n] = f2bf(hnew - bf2f(hi));
    if (fseq) fseq[(b << 10) + n] = hnew;
    if (hn)   hn  [(b << 10) + n] = hnew;
  }
}

// ---------------- host ----------------

extern "C" void kernel_launch(void* const* d_in, const int* in_sizes, int n_in,
                              void* d_out, int out_size, void* d_ws, size_t ws_size,
                              hipStream_t stream)
{
  (void)in_sizes; (void)n_in; (void)out_size; (void)ws_size;
  const float* X     = (const float*)d_in[0];
  const float* Wxrz0 = (const float*)d_in[1];
  const float* bxrz0 = (const float*)d_in[2];
  const float* Whrz0 = (const float*)d_in[3];
  const float* bhrz0 = (const float*)d_in[4];
  const float* Wxh0  = (const float*)d_in[5];
  const float* bxh0  = (const float*)d_in[6];
  const float* Whh0  = (const float*)d_in[7];
  const float* bhh0  = (const float*)d_in[8];
  const float* Wxrz1 = (const float*)d_in[9];
  const float* bxrz1 = (const float*)d_in[10];
  const float* Whrz1 = (const float*)d_in[11];
  const float* bhrz1 = (const float*)d_in[12];
  const float* Wxh1  = (const float*)d_in[13];
  const float* bxh1  = (const float*)d_in[14];
  const float* Whh1  = (const float*)d_in[15];
  const float* bhh1  = (const float*)d_in[16];

  char* p = (char*)d_ws;
  auto carve = [&](size_t bytes)->char*{
    char* r = p; p += (bytes + 255) & ~(size_t)255; return r;
  };
  unsigned short* Xbf    = (unsigned short*)carve((size_t)Mrows*512*2);   // 32MB
  unsigned short* W0t    = (unsigned short*)carve((size_t)3072*512*2);    // 3MB
  unsigned short* W1t    = (unsigned short*)carve((size_t)3072*1024*2);   // 6MB
  unsigned short* Whrz0t = (unsigned short*)carve((size_t)2048*1024*2);
  unsigned short* Whh0t  = (unsigned short*)carve((size_t)1024*1024*2);
  unsigned short* Whrz1t = (unsigned short*)carve((size_t)2048*1024*2);
  unsigned short* Whh1t  = (unsigned short*)carve((size_t)1024*1024*2);
  float* bias0 = (float*)carve(3072*4);
  float* bias1 = (float*)carve(3072*4);
  unsigned short* XprojRZ = (unsigned short*)carve((size_t)Mrows*2048*2); // 128MB (reused L0/L1)
  float*          XprojC  = (float*)carve((size_t)Mrows*1024*4);          // 128MB (reused L0/L1)
  unsigned short* H0seq   = (unsigned short*)carve((size_t)Mrows*1024*2); // 64MB
  float* h0fp = (float*)carve(Bz*Hh*4);
  float* h1fp = (float*)carve(Bz*Hh*4);
  unsigned short* h0lo   = (unsigned short*)carve(Bz*Hh*2);
  unsigned short* h1hi   = (unsigned short*)carve(Bz*Hh*2);
  unsigned short* h1lo   = (unsigned short*)carve(Bz*Hh*2);
  unsigned short* zerohi = (unsigned short*)carve(Bz*Hh*2);
  unsigned short* abhi   = (unsigned short*)carve(Bz*Hh*2);
  unsigned short* ablo   = (unsigned short*)carve(Bz*Hh*2);
  float* zbuf = (float*)carve(Bz*Hh*4);

  hipMemsetAsync(h0fp,   0, Bz*Hh*4, stream);
  hipMemsetAsync(h1fp,   0, Bz*Hh*4, stream);
  hipMemsetAsync(h0lo,   0, Bz*Hh*2, stream);
  hipMemsetAsync(h1hi,   0, Bz*Hh*2, stream);
  hipMemsetAsync(h1lo,   0, Bz*Hh*2, stream);
  hipMemsetAsync(zerohi, 0, Bz*Hh*2, stream);

  k_cvt_bf16<<<2048,256,0,stream>>>(X, Xbf, Mrows*512/4);
  k_transpose_bf16<<<dim3(8,32), 256,0,stream>>>(Wxrz0, W0t, 512, 2048);
  k_transpose_bf16<<<dim3(8,16), 256,0,stream>>>(Wxh0,  W0t + (size_t)2048*512, 512, 1024);
  k_transpose_bf16<<<dim3(16,32),256,0,stream>>>(Whrz0, Whrz0t, 1024, 2048);
  k_transpose_bf16<<<dim3(16,16),256,0,stream>>>(Whh0,  Whh0t, 1024, 1024);
  k_transpose_bf16<<<dim3(16,32),256,0,stream>>>(Wxrz1, W1t, 1024, 2048);
  k_transpose_bf16<<<dim3(16,16),256,0,stream>>>(Wxh1,  W1t + (size_t)2048*1024, 1024, 1024);
  k_transpose_bf16<<<dim3(16,32),256,0,stream>>>(Whrz1, Whrz1t, 1024, 2048);
  k_transpose_bf16<<<dim3(16,16),256,0,stream>>>(Whh1,  Whh1t, 1024, 1024);
  k_bias_fold<<<12,256,0,stream>>>(bxrz0, bhrz0, bxh0, bhh0, bias0);
  k_bias_fold<<<12,256,0,stream>>>(bxrz1, bhrz1, bxh1, bhh1, bias1);

  float* out = (float*)d_out;
  float* hn0 = out + (size_t)Mrows*Hh;
  float* hn1 = hn0 + Bz*Hh;

  // ---- layer 0 ----
  k_xproj_gemm<<<dim3(24,256),256,0,stream>>>(Xbf, W0t, bias0, XprojRZ, XprojC, 512);
  for (int t = 0; t < Tt; ++t){
    const unsigned short* hhi = t ? (H0seq + (size_t)(t-1)*Bz*Hh) : zerohi;
    k_stepA<<<128,256,0,stream>>>(hhi, h0lo, Whrz0t,
                                  XprojRZ + (size_t)t*Bz*2048, h0fp, abhi, ablo, zbuf);
    k_stepB<<<64,256,0,stream>>>(abhi, ablo, Whh0t,
                                 XprojC + (size_t)t*Bz*1024, zbuf, h0fp,
                                 H0seq + (size_t)t*Bz*Hh, h0lo,
                                 nullptr, (t==Tt-1)? hn0 : nullptr);
  }
  // ---- layer 1 ----
  k_xproj_gemm<<<dim3(24,256),256,0,stream>>>(H0seq, W1t, bias1, XprojRZ, XprojC, 1024);
  for (int t = 0; t < Tt; ++t){
    k_stepA<<<128,256,0,stream>>>(h1hi, h1lo, Whrz1t,
                                  XprojRZ + (size_t)t*Bz*2048, h1fp, abhi, ablo, zbuf);
    k_stepB<<<64,256,0,stream>>>(abhi, ablo, Whh1t,
                                 XprojC + (size_t)t*Bz*1024, zbuf, h1fp,
                                 h1hi, h1lo,
                                 out + (size_t)t*Bz*Hh, (t==Tt-1)? hn1 : nullptr);
  }
}